// Round 11
// baseline (153.896 us; speedup 1.0000x reference)
//
#include <hip/hip_runtime.h>

#define KE_KCAL 332.0637f

constexpr int N_ATOMS = 6144;
constexpr int NTILE = 1200;             // triangular 256x64 tiles
constexpr int NSPLIT = 4;               // j-tile split 64 -> 4 x 16
constexpr int NPAIRB = NTILE * NSPLIT;  // 4800 pair blocks
constexpr int NPRED = 384;              // pred blocks (16 atoms each)
constexpr int PAD = 32;                 // 128 B line stride

// ---------------- kernel A: pred + corr (in-kernel) + pack + zero scratch ---
// 384 blocks x 256 thr, 4 atoms/wave (R7 proven body). Block 0 zeroes
// epart/ctr1/ctr2. Last-finishing block (pred_ctr) computes
// corr = (Q_tot - sum qpart)/N and stores it (R9-proven atomic pattern).
__global__ __launch_bounds__(256) void pred_kernel(
    const float* __restrict__ f, const int* __restrict__ z,
    const float* __restrict__ w, const float* __restrict__ ztab,
    const float* __restrict__ xyz, const float* __restrict__ qtot,
    float* __restrict__ qpart, float4* __restrict__ xqp,
    float* __restrict__ epart, unsigned int* __restrict__ ctr1,
    unsigned int* __restrict__ ctr2, unsigned int* __restrict__ pred_ctr,
    float* __restrict__ cslot)
{
    int t = threadIdx.x, b = blockIdx.x;
    int lane = t & 63, wid = t >> 6;
    __shared__ float lred[4];
    __shared__ int lflag;

    if (b == 0) {
        if (t < 64) { epart[t * PAD] = 0.f; ctr1[t * PAD] = 0u; }
        if (t == 64) *ctr2 = 0u;
    }
    if (t == 0) lflag = 0;

    int base = b * 16 + wid * 4;
    const float2* f2 = (const float2*)f;
    float2 wv = ((const float2*)w)[lane];
    float2 v0 = f2[(size_t)(base + 0) * 64 + lane];
    float2 v1 = f2[(size_t)(base + 1) * 64 + lane];
    float2 v2 = f2[(size_t)(base + 2) * 64 + lane];
    float2 v3 = f2[(size_t)(base + 3) * 64 + lane];
    float p0 = fmaf(v0.x, wv.x, v0.y * wv.y);
    float p1 = fmaf(v1.x, wv.x, v1.y * wv.y);
    float p2 = fmaf(v2.x, wv.x, v2.y * wv.y);
    float p3 = fmaf(v3.x, wv.x, v3.y * wv.y);
    #pragma unroll
    for (int off = 32; off > 0; off >>= 1) {
        p0 += __shfl_xor(p0, off, 64);
        p1 += __shfl_xor(p1, off, 64);
        p2 += __shfl_xor(p2, off, 64);
        p3 += __shfl_xor(p3, off, 64);
    }
    float ws_sum = 0.f;
    if (lane < 4) {
        int atom = base + lane;
        float pk = p0;
        pk = (lane == 1) ? p1 : pk;
        pk = (lane == 2) ? p2 : pk;
        pk = (lane == 3) ? p3 : pk;
        pk += ztab[z[atom]];
        xqp[atom] = make_float4(xyz[3*atom], xyz[3*atom+1], xyz[3*atom+2], pk);
        ws_sum = pk;
    }
    ws_sum += __shfl_xor(ws_sum, 1, 64);
    ws_sum += __shfl_xor(ws_sum, 2, 64);
    if (lane == 0) lred[wid] = ws_sum;
    __syncthreads();
    if (t == 0) {
        qpart[b] = lred[0] + lred[1] + lred[2] + lred[3];
        unsigned int old = __hip_atomic_fetch_add(pred_ctr, 1u,
            __ATOMIC_ACQ_REL, __HIP_MEMORY_SCOPE_AGENT);
        if (old == NPRED - 1u) lflag = 1;
    }
    __syncthreads();
    if (lflag) {                        // last block: publish corr
        float s2 = 0.f;
        for (int k = t; k < NPRED; k += 256)
            s2 += __hip_atomic_load(&qpart[k], __ATOMIC_RELAXED,
                                    __HIP_MEMORY_SCOPE_AGENT);
        #pragma unroll
        for (int off = 32; off > 0; off >>= 1)
            s2 += __shfl_xor(s2, off, 64);
        if (lane == 0) lred[wid] = s2;
        __syncthreads();
        if (t == 0) {
            float S = lred[0] + lred[1] + lred[2] + lred[3];
            cslot[0] = (qtot[0] - S) * (1.0f / (float)N_ATOMS);
        }
    }
}

// ---------------- kernel B: pair energy, 4800 short blocks ------------------
// Block b: tile = b>>2 -> (bi,bj) triangular, s = b&3 selects 16-j sub-tile.
// 256 i-lanes x 16 j-iters: per-wave serial chain is 4x shorter than R7 and
// wave count is 4x higher (8 waves/SIMD) -> latency-stall coverage.
// Proven branchless switch math. corr precomputed by pred (1 scalar load).
__global__ __launch_bounds__(256) void pair_kernel(
    const float4* __restrict__ xqp, const float* __restrict__ cslot,
    float* __restrict__ qout, float* __restrict__ epart,
    unsigned int* __restrict__ ctr1, unsigned int* __restrict__ ctr2,
    float* __restrict__ out0)
{
    int t = threadIdx.x, b = blockIdx.x;
    int lane = t & 63, wid = t >> 6;
    __shared__ float lred[4];
    __shared__ float4 sj[16];

    float corr = cslot[0];              // uniform scalar load

    int tile = b >> 2, s = b & 3;
    int bi = 0, off = 0;
    while (tile >= off + (96 - 4 * bi)) { off += 96 - 4 * bi; ++bi; }
    int bj = 4 * bi + (tile - off);

    int gj0 = bj * 64 + s * 16;
    if (t < 16) {
        float4 a = xqp[gj0 + t];
        a.w += corr;
        sj[t] = a;
    }
    int gi = bi * 256 + t;
    float4 pi = xqp[gi];
    float qi = pi.w + corr;
    if (bj == 4 * bi && s == 0) qout[gi] = qi;   // one writer per i
    __syncthreads();

    int jthresh = gi - gj0;             // pair valid iff k > jthresh
    float acc = 0.f;
    #pragma unroll
    for (int k = 0; k < 16; ++k) {
        float4 pj = sj[k];
        float dx = pi.x - pj.x, dy = pi.y - pj.y, dz = pi.z - pj.z;
        float r2 = fmaf(dx, dx, fmaf(dy, dy, dz * dz));
        bool m = (k > jthresh) && (r2 > 0.f);
        float r2s = m ? r2 : 1e8f;
        float qq  = m ? qi * pj.w : 0.f;
        float t2  = __builtin_amdgcn_rsqf(r2s);            // 1/r
        float u   = fmaf(r2s * t2, 0.2f, -0.5f);           // (r-2.5)/5
        u = fminf(fmaxf(u, 1e-3f), 0.999f);                // exact 0/1 sat
        float d   = (u + u - 1.f) * __builtin_amdgcn_rcpf(fmaf(-u, u, u));
        float fs  = __builtin_amdgcn_rcpf(1.f + __expf(d));
        float t1  = __builtin_amdgcn_rsqf(r2s + 1.f);      // 1/sqrt(r2+1)
        acc = fmaf(qq, fmaf(fs, t1 - t2, t2), acc);
    }

    #pragma unroll
    for (int o2 = 32; o2 > 0; o2 >>= 1)
        acc += __shfl_down(acc, o2, 64);
    __syncthreads();                    // lred reuse
    if (lane == 0) lred[wid] = acc;
    __syncthreads();
    if (t == 0) {
        float be = lred[0] + lred[1] + lred[2] + lred[3];
        atomicAdd(&epart[(b & 63) * PAD], be);
    }

    // two-level completion + finalize (wave 0 only); 4800 = 64 groups x 75
    if (t < 64) {
        bool last = false;
        if (t == 0) {
            int g = b & 63;
            __threadfence();
            unsigned int o1 = atomicAdd(&ctr1[g * PAD], 1u);
            if (o1 == 74u) {
                __threadfence();
                unsigned int o2c = atomicAdd(ctr2, 1u);
                last = (o2c == 63u);
            }
        }
        last = (bool)__shfl((int)last, 0, 64);
        if (last) {
            float e = atomicAdd(&epart[t * PAD], 0.0f);   // coherent read
            #pragma unroll
            for (int o2 = 32; o2 > 0; o2 >>= 1)
                e += __shfl_down(e, o2, 64);
            if (t == 0) out0[0] = KE_KCAL * e;
        }
    }
}

extern "C" void kernel_launch(void* const* d_in, const int* in_sizes, int n_in,
                              void* d_out, int out_size, void* d_ws, size_t ws_size,
                              hipStream_t stream) {
    const float* f    = (const float*)d_in[0];
    const int*   z    = (const int*)  d_in[1];
    const float* xyz  = (const float*)d_in[2];
    const float* qtot = (const float*)d_in[3];
    const float* w    = (const float*)d_in[4];
    const float* ztab = (const float*)d_in[5];
    float* out = (float*)d_out;            // out[0]=energy, out[1..N]=q

    // ws: [0,8192) epart padded | [8192,16384) ctr1 padded | [16384] ctr2
    //     [16388] pred_ctr | [16392] cslot | [16896,+1536) qpart[384]
    //     [32768,+98304) xqp[N] float4
    char* wsb = (char*)d_ws;
    float*        epart    = (float*)(wsb + 0);
    unsigned int* ctr1     = (unsigned int*)(wsb + 8192);
    unsigned int* ctr2     = (unsigned int*)(wsb + 16384);
    unsigned int* pred_ctr = (unsigned int*)(wsb + 16388);
    float*        cslot    = (float*)(wsb + 16392);
    float*        qpart    = (float*)(wsb + 16896);
    float4*       xqp      = (float4*)(wsb + 32768);

    // pred_ctr must start at 0 (no memset dispatch): zero via small kernel?
    // No — fold into pred: it uses fetch_add wrap detection instead.
    // Simplest safe option: hipMemsetAsync of 4 bytes (graph-capture safe).
    hipMemsetAsync(pred_ctr, 0, sizeof(unsigned int), stream);

    pred_kernel<<<NPRED, 256, 0, stream>>>(f, z, w, ztab, xyz, qtot,
                                           qpart, xqp, epart, ctr1, ctr2,
                                           pred_ctr, cslot);
    pair_kernel<<<NPAIRB, 256, 0, stream>>>(xqp, cslot, out + 1, epart,
                                            ctr1, ctr2, out);
}

// Round 12
// 90.252 us; speedup vs baseline: 1.7052x; 1.7052x over previous
//
#include <hip/hip_runtime.h>

#define KE_KCAL 332.0637f

constexpr int N_ATOMS = 6144;
constexpr int NREAL = 1200;             // triangular 256x64 tiles
constexpr int NPRED = 384;              // pred blocks (16 atoms each)

// ---------------- kernel A: pred + per-block sums + pack --------------------
// 384 blocks x 256 thr, 4 atoms/wave (R7 proven body). Plain stores only.
__global__ __launch_bounds__(256) void pred_kernel(
    const float* __restrict__ f, const int* __restrict__ z,
    const float* __restrict__ w, const float* __restrict__ ztab,
    const float* __restrict__ xyz,
    float* __restrict__ qpart, float4* __restrict__ xqp)
{
    int t = threadIdx.x, b = blockIdx.x;
    int lane = t & 63, wid = t >> 6;

    int base = b * 16 + wid * 4;
    const float2* f2 = (const float2*)f;
    float2 wv = ((const float2*)w)[lane];
    float2 v0 = f2[(size_t)(base + 0) * 64 + lane];
    float2 v1 = f2[(size_t)(base + 1) * 64 + lane];
    float2 v2 = f2[(size_t)(base + 2) * 64 + lane];
    float2 v3 = f2[(size_t)(base + 3) * 64 + lane];
    float p0 = fmaf(v0.x, wv.x, v0.y * wv.y);
    float p1 = fmaf(v1.x, wv.x, v1.y * wv.y);
    float p2 = fmaf(v2.x, wv.x, v2.y * wv.y);
    float p3 = fmaf(v3.x, wv.x, v3.y * wv.y);
    #pragma unroll
    for (int off = 32; off > 0; off >>= 1) {
        p0 += __shfl_xor(p0, off, 64);
        p1 += __shfl_xor(p1, off, 64);
        p2 += __shfl_xor(p2, off, 64);
        p3 += __shfl_xor(p3, off, 64);
    }
    float ws_sum = 0.f;
    if (lane < 4) {
        int atom = base + lane;
        float pk = p0;
        pk = (lane == 1) ? p1 : pk;
        pk = (lane == 2) ? p2 : pk;
        pk = (lane == 3) ? p3 : pk;
        pk += ztab[z[atom]];
        xqp[atom] = make_float4(xyz[3*atom], xyz[3*atom+1], xyz[3*atom+2], pk);
        ws_sum = pk;
    }
    ws_sum += __shfl_xor(ws_sum, 1, 64);
    ws_sum += __shfl_xor(ws_sum, 2, 64);

    __shared__ float lred[4];
    if (lane == 0) lred[wid] = ws_sum;
    __syncthreads();
    if (t == 0) qpart[b] = lred[0] + lred[1] + lred[2] + lred[3];
}

// ---------------- kernel B: pair energy, software-pipelined -----------------
// 1200 triangular blocks x 256 thr. 64-j tile in LDS; inner loop manually
// pipelined: prefetch next 4 j into registers while computing current 4 on
// 4 independent accumulator chains (ILP=4, LDS latency off critical path).
// No atomics, no fences: plain eblk[b] store; finalize is a 3rd dispatch.
__global__ __launch_bounds__(256) void pair_kernel(
    const float4* __restrict__ xqp, const float* __restrict__ qpart,
    const float* __restrict__ total_charge,
    float* __restrict__ qout, float* __restrict__ eblk)
{
    int t = threadIdx.x, b = blockIdx.x;
    int lane = t & 63, wid = t >> 6;
    __shared__ float lred[4];
    __shared__ float4 sj[64];

    // charge correction from the 384 per-block partials
    float s = qpart[t];
    if (t < NPRED - 256) s += qpart[256 + t];
    #pragma unroll
    for (int off = 32; off > 0; off >>= 1)
        s += __shfl_xor(s, off, 64);
    if (lane == 0) lred[wid] = s;
    __syncthreads();
    float S = lred[0] + lred[1] + lred[2] + lred[3];
    float corr = (total_charge[0] - S) * (1.0f / (float)N_ATOMS);

    // decode triangular (bi, bj): bj in [4*bi, 96)
    int bi = 0, off = 0;
    while (b >= off + (96 - 4 * bi)) { off += 96 - 4 * bi; ++bi; }
    int bj = 4 * bi + (b - off);

    int gj0 = bj * 64;
    if (t < 64) {
        float4 a = xqp[gj0 + t];
        a.w += corr;
        sj[t] = a;
    }
    int gi = bi * 256 + t;
    float4 pi = xqp[gi];
    float qi = pi.w + corr;
    if (bj == 4 * bi) qout[gi] = qi;
    __syncthreads();

    int jthresh = gi - gj0;             // pair valid iff jj > jthresh

    // software-pipelined loop: prefetch distance 4, 4 accumulator chains
    float4 c0 = sj[0], c1 = sj[1], c2 = sj[2], c3 = sj[3];
    float acc0 = 0.f, acc1 = 0.f, acc2 = 0.f, acc3 = 0.f;
    #pragma unroll
    for (int k = 0; k < 64; k += 4) {
        float4 n0, n1, n2, n3;
        if (k + 4 < 64) {               // compile-time per unrolled copy
            n0 = sj[k+4]; n1 = sj[k+5]; n2 = sj[k+6]; n3 = sj[k+7];
        }
        {
            float dx = pi.x - c0.x, dy = pi.y - c0.y, dz = pi.z - c0.z;
            float r2 = fmaf(dx, dx, fmaf(dy, dy, dz * dz));
            bool m = (k > jthresh) && (r2 > 0.f);
            float r2s = m ? r2 : 1e8f;
            float qq  = m ? qi * c0.w : 0.f;
            float t2 = __builtin_amdgcn_rsqf(r2s);
            float u  = fmaf(r2s * t2, 0.2f, -0.5f);
            u = fminf(fmaxf(u, 1e-3f), 0.999f);
            float d  = (u + u - 1.f) * __builtin_amdgcn_rcpf(fmaf(-u, u, u));
            float fs = __builtin_amdgcn_rcpf(1.f + __expf(d));
            float t1 = __builtin_amdgcn_rsqf(r2s + 1.f);
            acc0 = fmaf(qq, fmaf(fs, t1 - t2, t2), acc0);
        }
        {
            float dx = pi.x - c1.x, dy = pi.y - c1.y, dz = pi.z - c1.z;
            float r2 = fmaf(dx, dx, fmaf(dy, dy, dz * dz));
            bool m = (k + 1 > jthresh) && (r2 > 0.f);
            float r2s = m ? r2 : 1e8f;
            float qq  = m ? qi * c1.w : 0.f;
            float t2 = __builtin_amdgcn_rsqf(r2s);
            float u  = fmaf(r2s * t2, 0.2f, -0.5f);
            u = fminf(fmaxf(u, 1e-3f), 0.999f);
            float d  = (u + u - 1.f) * __builtin_amdgcn_rcpf(fmaf(-u, u, u));
            float fs = __builtin_amdgcn_rcpf(1.f + __expf(d));
            float t1 = __builtin_amdgcn_rsqf(r2s + 1.f);
            acc1 = fmaf(qq, fmaf(fs, t1 - t2, t2), acc1);
        }
        {
            float dx = pi.x - c2.x, dy = pi.y - c2.y, dz = pi.z - c2.z;
            float r2 = fmaf(dx, dx, fmaf(dy, dy, dz * dz));
            bool m = (k + 2 > jthresh) && (r2 > 0.f);
            float r2s = m ? r2 : 1e8f;
            float qq  = m ? qi * c2.w : 0.f;
            float t2 = __builtin_amdgcn_rsqf(r2s);
            float u  = fmaf(r2s * t2, 0.2f, -0.5f);
            u = fminf(fmaxf(u, 1e-3f), 0.999f);
            float d  = (u + u - 1.f) * __builtin_amdgcn_rcpf(fmaf(-u, u, u));
            float fs = __builtin_amdgcn_rcpf(1.f + __expf(d));
            float t1 = __builtin_amdgcn_rsqf(r2s + 1.f);
            acc2 = fmaf(qq, fmaf(fs, t1 - t2, t2), acc2);
        }
        {
            float dx = pi.x - c3.x, dy = pi.y - c3.y, dz = pi.z - c3.z;
            float r2 = fmaf(dx, dx, fmaf(dy, dy, dz * dz));
            bool m = (k + 3 > jthresh) && (r2 > 0.f);
            float r2s = m ? r2 : 1e8f;
            float qq  = m ? qi * c3.w : 0.f;
            float t2 = __builtin_amdgcn_rsqf(r2s);
            float u  = fmaf(r2s * t2, 0.2f, -0.5f);
            u = fminf(fmaxf(u, 1e-3f), 0.999f);
            float d  = (u + u - 1.f) * __builtin_amdgcn_rcpf(fmaf(-u, u, u));
            float fs = __builtin_amdgcn_rcpf(1.f + __expf(d));
            float t1 = __builtin_amdgcn_rsqf(r2s + 1.f);
            acc3 = fmaf(qq, fmaf(fs, t1 - t2, t2), acc3);
        }
        c0 = n0; c1 = n1; c2 = n2; c3 = n3;
    }
    float acc = (acc0 + acc1) + (acc2 + acc3);

    #pragma unroll
    for (int o2 = 32; o2 > 0; o2 >>= 1)
        acc += __shfl_down(acc, o2, 64);
    __syncthreads();                    // lred reuse
    if (lane == 0) lred[wid] = acc;
    __syncthreads();
    if (t == 0) eblk[b] = lred[0] + lred[1] + lred[2] + lred[3];
}

// ---------------- kernel C: finalize energy ---------------------------------
__global__ __launch_bounds__(256) void efin_kernel(
    const float* __restrict__ eblk, float* __restrict__ out0)
{
    int t = threadIdx.x;
    float e = 0.f;
    for (int k = t; k < NREAL; k += 256) e += eblk[k];
    #pragma unroll
    for (int o2 = 32; o2 > 0; o2 >>= 1)
        e += __shfl_down(e, o2, 64);
    __shared__ float wacc[4];
    if ((t & 63) == 0) wacc[t >> 6] = e;
    __syncthreads();
    if (t == 0) out0[0] = KE_KCAL * (wacc[0] + wacc[1] + wacc[2] + wacc[3]);
}

extern "C" void kernel_launch(void* const* d_in, const int* in_sizes, int n_in,
                              void* d_out, int out_size, void* d_ws, size_t ws_size,
                              hipStream_t stream) {
    const float* f    = (const float*)d_in[0];
    const int*   z    = (const int*)  d_in[1];
    const float* xyz  = (const float*)d_in[2];
    const float* qtot = (const float*)d_in[3];
    const float* w    = (const float*)d_in[4];
    const float* ztab = (const float*)d_in[5];
    float* out = (float*)d_out;            // out[0]=energy, out[1..N]=q

    // ws: [0, 1536) qpart[384] | [2048, 2048+4800) eblk[1200]
    //     [16384, +98304) xqp[N] float4   (no zeroing needed anywhere)
    char* wsb = (char*)d_ws;
    float*  qpart = (float*)(wsb + 0);
    float*  eblk  = (float*)(wsb + 2048);
    float4* xqp   = (float4*)(wsb + 16384);

    pred_kernel<<<NPRED, 256, 0, stream>>>(f, z, w, ztab, xyz, qpart, xqp);
    pair_kernel<<<NREAL, 256, 0, stream>>>(xqp, qpart, qtot, out + 1, eblk);
    efin_kernel<<<1, 256, 0, stream>>>(eblk, out);
}